// Round 3
// baseline (2996.077 us; speedup 1.0000x reference)
//
#include <hip/hip_runtime.h>
#include <hip/hip_bf16.h>

// Problem: 2-layer GraphSAGE mean-aggr, N=100000, E=1600000, F=128.
// layer: out = (scatter_mean(x[src] -> dst)) @ W_l + x @ W_r + b
// R2: CRITICAL FIX — harness delivers integer inputs as int32 ("integer ->
// const int*"), not int64. R0/R1 cast edge_index to long long -> OOB reads
// + atomics to garbage addresses -> core dump. Now const int*.
//   - deg + sum via HW fp32 atomics (64 lanes/edge, float2 gather per lane)
//   - fused GEMM per layer: A=[mean|x] (Nx256) @ B=[W_l;W_r] (256x128) + bias (+relu)

#define N_NODES 100000
#define N_EDGES 1600000
#define F 128

// ---------------- scatter: sums += x[src], deg += 1 ----------------
__global__ __launch_bounds__(256) void scatter_sum_kernel(
    const float* __restrict__ feat, const int* __restrict__ ei,
    float* __restrict__ sums, float* __restrict__ deg, int E)
{
    int edge = (blockIdx.x << 2) + (threadIdx.x >> 6);  // 4 edges per 256-thr block
    int lane = threadIdx.x & 63;
    if (edge >= E) return;
    int s = ei[edge];        // src row
    int d = ei[E + edge];    // dst row
    const float2 v = *(const float2*)(feat + (size_t)s * F + lane * 2);
    float* dp = sums + (size_t)d * F + lane * 2;
    unsafeAtomicAdd(dp,     v.x);
    unsafeAtomicAdd(dp + 1, v.y);
    if (deg != nullptr && lane == 0) unsafeAtomicAdd(deg + d, 1.0f);
}

// ---------------- fused SAGE layer GEMM ----------------
// out[i][:] = (sum[i]/max(deg[i],1)) @ Wl + xin[i] @ Wr + bias  (+relu)
// Tiling: BM=64 nodes, BN=128 (all cols), K=256 in 4 chunks of 64.
// NOTE: safe for out==xin aliasing — a block reads only its own rows of xin
// (chunks 2,3), all before the epilogue writes those same rows.
#define BM 64
#define KC 64
#define BN 128

template <bool RELU>
__global__ __launch_bounds__(256) void sage_gemm_kernel(
    const float* __restrict__ sums, const float* __restrict__ deg,
    const float* __restrict__ xin,
    const float* __restrict__ Wl, const float* __restrict__ Wr,
    const float* __restrict__ bias, float* __restrict__ out, int N)
{
    __shared__ float As[KC][BM + 1];   // [k][node], +1 pad
    __shared__ float Bs[KC][BN];       // [k][col]

    const int t = threadIdx.x;
    const int block_row = blockIdx.x * BM;
    const int tr = t >> 4;             // 0..15
    const int tc = t & 15;             // 0..15
    const int r0 = tr * 4;             // 4 nodes per thread
    const int c0 = tc * 8;             // 8 cols per thread

    float acc[4][8];
#pragma unroll
    for (int i = 0; i < 4; ++i)
#pragma unroll
        for (int j = 0; j < 8; ++j) acc[i][j] = 0.0f;

    for (int chunk = 0; chunk < 4; ++chunk) {
        const bool is_mean = (chunk < 2);
        const float* Asrc = is_mean ? sums : xin;
        const float* Bsrc = is_mean ? Wl : Wr;
        const int kbase = (chunk & 1) * KC;   // col offset within 128-wide source

        // --- load A tile: 64 nodes x 64 k (1024 float4 granules, 4/thread) ---
#pragma unroll
        for (int i = 0; i < 4; ++i) {
            int g = t + 256 * i;
            int node = g >> 4;       // 0..63
            int kq = g & 15;         // 0..15 (float4 granule within k-chunk)
            int row = block_row + node;
            float4 v = make_float4(0.f, 0.f, 0.f, 0.f);
            if (row < N) {
                v = *(const float4*)(Asrc + (size_t)row * F + kbase + kq * 4);
                if (is_mean) {
                    float r = 1.0f / fmaxf(deg[row], 1.0f);
                    v.x *= r; v.y *= r; v.z *= r; v.w *= r;
                }
            }
            int kk = kq * 4;
            As[kk + 0][node] = v.x;
            As[kk + 1][node] = v.y;
            As[kk + 2][node] = v.z;
            As[kk + 3][node] = v.w;
        }

        // --- load B tile: rows kbase..kbase+63 of Wsrc (2048 granules, 8/thread) ---
#pragma unroll
        for (int i = 0; i < 8; ++i) {
            int g = t + 256 * i;
            int kk = g >> 5;         // 0..63
            int cq = g & 31;         // 0..31
            float4 v = *(const float4*)(Bsrc + (size_t)(kbase + kk) * BN + cq * 4);
            *(float4*)(&Bs[kk][cq * 4]) = v;
        }
        __syncthreads();

        // --- FMA microkernel: 4x8 per thread ---
        for (int kk = 0; kk < KC; ++kk) {
            float av[4];
#pragma unroll
            for (int i = 0; i < 4; ++i) av[i] = As[kk][r0 + i];
            float bv[8];
            float4 b0 = *(const float4*)(&Bs[kk][c0]);
            float4 b1 = *(const float4*)(&Bs[kk][c0 + 4]);
            bv[0] = b0.x; bv[1] = b0.y; bv[2] = b0.z; bv[3] = b0.w;
            bv[4] = b1.x; bv[5] = b1.y; bv[6] = b1.z; bv[7] = b1.w;
#pragma unroll
            for (int i = 0; i < 4; ++i)
#pragma unroll
                for (int j = 0; j < 8; ++j) acc[i][j] += av[i] * bv[j];
        }
        __syncthreads();
    }

    // --- epilogue: bias (+relu), vectorized store ---
    float bb[8];
#pragma unroll
    for (int j = 0; j < 8; ++j) bb[j] = bias[c0 + j];
#pragma unroll
    for (int i = 0; i < 4; ++i) {
        int row = block_row + r0 + i;
        if (row < N) {
            float vals[8];
#pragma unroll
            for (int j = 0; j < 8; ++j) {
                float v = acc[i][j] + bb[j];
                if (RELU) v = fmaxf(v, 0.0f);
                vals[j] = v;
            }
            *(float4*)(out + (size_t)row * F + c0) =
                make_float4(vals[0], vals[1], vals[2], vals[3]);
            *(float4*)(out + (size_t)row * F + c0 + 4) =
                make_float4(vals[4], vals[5], vals[6], vals[7]);
        }
    }
}

extern "C" void kernel_launch(void* const* d_in, const int* in_sizes, int n_in,
                              void* d_out, int out_size, void* d_ws, size_t ws_size,
                              hipStream_t stream) {
    const float* x        = (const float*)d_in[0];
    const int*   ei       = (const int*)d_in[1];    // int32! (harness converts int64)
    const float* W_l1     = (const float*)d_in[2];
    const float* W_r1     = (const float*)d_in[3];
    const float* b1       = (const float*)d_in[4];
    const float* W_l2     = (const float*)d_in[5];
    const float* W_r2     = (const float*)d_in[6];
    const float* b2       = (const float*)d_in[7];
    float* out            = (float*)d_out;

    const int N = N_NODES;
    const int E = N_EDGES;

    const size_t sums_bytes = (size_t)N * F * sizeof(float);   // 51.2 MB
    const size_t sums_off   = 400384;                          // deg: 400000 B, 16B-aligned pad
    const size_t need_small = sums_off + sums_bytes;           // ~51.6 MB
    const size_t need_big   = need_small + sums_bytes;         // ~102.8 MB

    if (ws_size < need_small) {
        // Cannot run: leave output untouched -> clean validation failure
        // (diagnostic signal), instead of OOB writes.
        return;
    }

    char* ws = (char*)d_ws;
    float* deg  = (float*)ws;
    float* sums = (float*)(ws + sums_off);
    // Intermediate h: prefer ws if it fits, else alias onto d_out (safe, see note).
    float* h = (ws_size >= need_big) ? (float*)(ws + need_small) : out;

    // ---- layer 1 ----
    hipMemsetAsync(deg, 0, (size_t)N * sizeof(float), stream);
    hipMemsetAsync(sums, 0, sums_bytes, stream);

    dim3 sblock(256);
    dim3 sgrid((E + 3) / 4);
    scatter_sum_kernel<<<sgrid, sblock, 0, stream>>>(x, ei, sums, deg, E);

    dim3 gblock(256);
    dim3 ggrid((N + BM - 1) / BM);
    sage_gemm_kernel<true><<<ggrid, gblock, 0, stream>>>(
        sums, deg, x, W_l1, W_r1, b1, h, N);

    // ---- layer 2 ----
    hipMemsetAsync(sums, 0, sums_bytes, stream);
    scatter_sum_kernel<<<sgrid, sblock, 0, stream>>>(h, ei, sums, nullptr, E);

    sage_gemm_kernel<false><<<ggrid, gblock, 0, stream>>>(
        sums, deg, h, W_l2, W_r2, b2, out, N);
}

// Round 4
// 714.656 us; speedup vs baseline: 4.1923x; 4.1923x over previous
//
#include <hip/hip_runtime.h>
#include <hip/hip_bf16.h>

// Problem: 2-layer GraphSAGE mean-aggr, N=100000, E=1600000, F=128.
// layer: out = (scatter_mean(x[src] -> dst)) @ W_l + x @ W_r + b
// R3: replace fp32-atomic scatter (2x1375us, 92% of runtime, 1.65GB HBM
// writes each from near-memory RMW) with CSR counting-sort + node-parallel
// gather-mean. Mean stored bf16 (threshold is 3.5e-2; R2 absmax 3.9e-3).
//   build: histogram -> 3-kernel exclusive scan -> cursor fill (int atomics only)
//   aggregate: 1 wave/node, float2/lane gather of x[src], fp32 acc, bf16 store
//   GEMM: A=[mean_bf16 | x_f32] (Nx256) @ [Wl;Wr] (256x128) + bias (+relu)

#define N_NODES 100000
#define N_EDGES 1600000
#define F 128
#define NB 391              // ceil(N/256)

__device__ __forceinline__ float bf2f(unsigned short u) {
    return __uint_as_float(((unsigned)u) << 16);
}

// ---------------- CSR build ----------------
__global__ __launch_bounds__(256) void hist_kernel(
    const int* __restrict__ dst, int* __restrict__ deg_i, int E)
{
    int e = blockIdx.x * 256 + threadIdx.x;
    if (e < E) atomicAdd(&deg_i[dst[e]], 1);
}

__global__ __launch_bounds__(256) void partial_sum_kernel(
    const int* __restrict__ deg_i, int* __restrict__ partial, int N)
{
    int i = blockIdx.x * 256 + threadIdx.x;
    int d = (i < N) ? deg_i[i] : 0;
#pragma unroll
    for (int off = 32; off > 0; off >>= 1) d += __shfl_down(d, off, 64);
    __shared__ int ws[4];
    if ((threadIdx.x & 63) == 0) ws[threadIdx.x >> 6] = d;
    __syncthreads();
    if (threadIdx.x == 0) partial[blockIdx.x] = ws[0] + ws[1] + ws[2] + ws[3];
}

__global__ __launch_bounds__(512) void scan_partial_kernel(int* partial)
{
    __shared__ int s[512];
    int t = threadIdx.x;
    s[t] = (t < NB) ? partial[t] : 0;
    __syncthreads();
#pragma unroll
    for (int off = 1; off < 512; off <<= 1) {
        int v = (t >= off) ? s[t - off] : 0;
        __syncthreads();
        s[t] += v;
        __syncthreads();
    }
    // exclusive-of-blocks
    partial[t] = (t == 0) ? 0 : s[t - 1];
}

__global__ __launch_bounds__(256) void rowptr_kernel(
    const int* __restrict__ deg_i, const int* __restrict__ partial,
    int* __restrict__ rowptr, int* __restrict__ cursor, int N)
{
    __shared__ int s[256];
    int t = threadIdx.x;
    int i = blockIdx.x * 256 + t;
    int d = (i < N) ? deg_i[i] : 0;
    s[t] = d;
    __syncthreads();
#pragma unroll
    for (int off = 1; off < 256; off <<= 1) {
        int v = (t >= off) ? s[t - off] : 0;
        __syncthreads();
        s[t] += v;
        __syncthreads();
    }
    if (i < N) {
        int r = partial[blockIdx.x] + s[t] - d;   // exclusive
        rowptr[i] = r;
        cursor[i] = r;
    }
}

__global__ __launch_bounds__(256) void fill_kernel(
    const int* __restrict__ src, const int* __restrict__ dst,
    int* __restrict__ cursor, int* __restrict__ csr_src, int E)
{
    int e = blockIdx.x * 256 + threadIdx.x;
    if (e < E) {
        int pos = atomicAdd(&cursor[dst[e]], 1);
        csr_src[pos] = src[e];
    }
}

// ---------------- aggregate: mean over neighbors, bf16 out ----------------
__global__ __launch_bounds__(256) void csr_mean_kernel(
    const float* __restrict__ feat, const int* __restrict__ rowptr,
    const int* __restrict__ deg_i, const int* __restrict__ csr_src,
    __hip_bfloat16* __restrict__ mean, int N)
{
    int n = blockIdx.x * 4 + (threadIdx.x >> 6);
    int lane = threadIdx.x & 63;
    if (n >= N) return;
    int start = rowptr[n];
    int dg = deg_i[n];
    int end = start + dg;
    float ax = 0.f, ay = 0.f;
    int e = start;
    for (; e + 1 < end; e += 2) {
        int s0 = csr_src[e], s1 = csr_src[e + 1];
        float2 v0 = *(const float2*)(feat + (size_t)s0 * F + lane * 2);
        float2 v1 = *(const float2*)(feat + (size_t)s1 * F + lane * 2);
        ax += v0.x + v1.x;
        ay += v0.y + v1.y;
    }
    if (e < end) {
        int s0 = csr_src[e];
        float2 v0 = *(const float2*)(feat + (size_t)s0 * F + lane * 2);
        ax += v0.x;
        ay += v0.y;
    }
    float r = 1.0f / fmaxf((float)dg, 1.0f);
    __hip_bfloat16* mp = mean + (size_t)n * F + lane * 2;
    mp[0] = __float2bfloat16(ax * r);
    mp[1] = __float2bfloat16(ay * r);
}

// ---------------- fused SAGE layer GEMM ----------------
// out[i][:] = mean[i] @ Wl + xin[i] @ Wr + bias  (+relu)
// BM=64 nodes, BN=128 cols, K=256 in 4 chunks of 64.
// Safe for out==xin aliasing: block reads only its own rows before epilogue.
#define BM 64
#define KC 64
#define BN 128

template <bool RELU>
__global__ __launch_bounds__(256) void sage_gemm_kernel(
    const __hip_bfloat16* __restrict__ mean,
    const float* __restrict__ xin,
    const float* __restrict__ Wl, const float* __restrict__ Wr,
    const float* __restrict__ bias, float* __restrict__ out, int N)
{
    __shared__ float As[KC][BM + 1];
    __shared__ float Bs[KC][BN];

    const int t = threadIdx.x;
    const int block_row = blockIdx.x * BM;
    const int tr = t >> 4;
    const int tc = t & 15;
    const int r0 = tr * 4;
    const int c0 = tc * 8;

    float acc[4][8];
#pragma unroll
    for (int i = 0; i < 4; ++i)
#pragma unroll
        for (int j = 0; j < 8; ++j) acc[i][j] = 0.0f;

    for (int chunk = 0; chunk < 4; ++chunk) {
        const bool is_mean = (chunk < 2);
        const float* Bsrc = is_mean ? Wl : Wr;
        const int kbase = (chunk & 1) * KC;

        // --- A tile: 64 nodes x 64 k ---
#pragma unroll
        for (int i = 0; i < 4; ++i) {
            int g = t + 256 * i;
            int node = g >> 4;
            int kq = g & 15;
            int row = block_row + node;
            float4 v = make_float4(0.f, 0.f, 0.f, 0.f);
            if (row < N) {
                if (is_mean) {
                    ushort4 u = *(const ushort4*)((const unsigned short*)mean +
                                                  (size_t)row * F + kbase + kq * 4);
                    v = make_float4(bf2f(u.x), bf2f(u.y), bf2f(u.z), bf2f(u.w));
                } else {
                    v = *(const float4*)(xin + (size_t)row * F + kbase + kq * 4);
                }
            }
            int kk = kq * 4;
            As[kk + 0][node] = v.x;
            As[kk + 1][node] = v.y;
            As[kk + 2][node] = v.z;
            As[kk + 3][node] = v.w;
        }

        // --- B tile ---
#pragma unroll
        for (int i = 0; i < 8; ++i) {
            int g = t + 256 * i;
            int kk = g >> 5;
            int cq = g & 31;
            float4 v = *(const float4*)(Bsrc + (size_t)(kbase + kk) * BN + cq * 4);
            *(float4*)(&Bs[kk][cq * 4]) = v;
        }
        __syncthreads();

        for (int kk = 0; kk < KC; ++kk) {
            float av[4];
#pragma unroll
            for (int i = 0; i < 4; ++i) av[i] = As[kk][r0 + i];
            float bv[8];
            float4 b0 = *(const float4*)(&Bs[kk][c0]);
            float4 b1 = *(const float4*)(&Bs[kk][c0 + 4]);
            bv[0] = b0.x; bv[1] = b0.y; bv[2] = b0.z; bv[3] = b0.w;
            bv[4] = b1.x; bv[5] = b1.y; bv[6] = b1.z; bv[7] = b1.w;
#pragma unroll
            for (int i = 0; i < 4; ++i)
#pragma unroll
                for (int j = 0; j < 8; ++j) acc[i][j] += av[i] * bv[j];
        }
        __syncthreads();
    }

    float bb[8];
#pragma unroll
    for (int j = 0; j < 8; ++j) bb[j] = bias[c0 + j];
#pragma unroll
    for (int i = 0; i < 4; ++i) {
        int row = block_row + r0 + i;
        if (row < N) {
            float vals[8];
#pragma unroll
            for (int j = 0; j < 8; ++j) {
                float v = acc[i][j] + bb[j];
                if (RELU) v = fmaxf(v, 0.0f);
                vals[j] = v;
            }
            *(float4*)(out + (size_t)row * F + c0) =
                make_float4(vals[0], vals[1], vals[2], vals[3]);
            *(float4*)(out + (size_t)row * F + c0 + 4) =
                make_float4(vals[4], vals[5], vals[6], vals[7]);
        }
    }
}

extern "C" void kernel_launch(void* const* d_in, const int* in_sizes, int n_in,
                              void* d_out, int out_size, void* d_ws, size_t ws_size,
                              hipStream_t stream) {
    const float* x    = (const float*)d_in[0];
    const int*   ei   = (const int*)d_in[1];    // int32 (harness converts int64)
    const float* W_l1 = (const float*)d_in[2];
    const float* W_r1 = (const float*)d_in[3];
    const float* b1   = (const float*)d_in[4];
    const float* W_l2 = (const float*)d_in[5];
    const float* W_r2 = (const float*)d_in[6];
    const float* b2   = (const float*)d_in[7];
    float* out        = (float*)d_out;

    const int N = N_NODES;
    const int E = N_EDGES;
    const int* src = ei;
    const int* dst = ei + E;

    // ---- workspace layout (bytes) ----
    const size_t deg_off    = 0;                 // int[100352]
    const size_t rowptr_off = 401408;
    const size_t cursor_off = 802816;
    const size_t part_off   = 1204224;           // int[512]
    const size_t csr_off    = 1206272;           // int[1.6M]
    const size_t mean_off   = 7606272;           // bf16[N*F] = 25.6 MB
    const size_t need_small = mean_off + (size_t)N * F * 2;          // ~33.2 MB
    const size_t need_big   = need_small + (size_t)N * F * 4;        // ~84.4 MB

    if (ws_size < need_small) return;  // clean validation failure as diagnostic

    char* ws = (char*)d_ws;
    int* deg_i   = (int*)(ws + deg_off);
    int* rowptr  = (int*)(ws + rowptr_off);
    int* cursor  = (int*)(ws + cursor_off);
    int* partial = (int*)(ws + part_off);
    int* csr_src = (int*)(ws + csr_off);
    __hip_bfloat16* meanb = (__hip_bfloat16*)(ws + mean_off);
    float* h = (ws_size >= need_big) ? (float*)(ws + need_small) : out;

    // ---- CSR build (graph-only; rebuilt every call per harness contract) ----
    hipMemsetAsync(deg_i, 0, (size_t)N * sizeof(int), stream);
    hist_kernel<<<dim3((E + 255) / 256), dim3(256), 0, stream>>>(dst, deg_i, E);
    partial_sum_kernel<<<dim3(NB), dim3(256), 0, stream>>>(deg_i, partial, N);
    scan_partial_kernel<<<dim3(1), dim3(512), 0, stream>>>(partial);
    rowptr_kernel<<<dim3(NB), dim3(256), 0, stream>>>(deg_i, partial, rowptr, cursor, N);
    fill_kernel<<<dim3((E + 255) / 256), dim3(256), 0, stream>>>(src, dst, cursor, csr_src, E);

    dim3 ablock(256), agrid((N + 3) / 4);
    dim3 gblock(256), ggrid((N + BM - 1) / BM);

    // ---- layer 1 ----
    csr_mean_kernel<<<agrid, ablock, 0, stream>>>(x, rowptr, deg_i, csr_src, meanb, N);
    sage_gemm_kernel<true><<<ggrid, gblock, 0, stream>>>(
        meanb, x, W_l1, W_r1, b1, h, N);

    // ---- layer 2 ----
    csr_mean_kernel<<<agrid, ablock, 0, stream>>>(h, rowptr, deg_i, csr_src, meanb, N);
    sage_gemm_kernel<false><<<ggrid, gblock, 0, stream>>>(
        meanb, h, W_l2, W_r2, b2, out, N);
}

// Round 5
// 551.239 us; speedup vs baseline: 5.4352x; 1.2965x over previous
//
#include <hip/hip_runtime.h>
#include <hip/hip_bf16.h>

// 2-layer GraphSAGE mean-aggr, N=100000, E=1600000, F=128.
// R4: bf16 MFMA GEMM (16x16x32) + bf16 x-cast for halved L1 gather traffic.
//   - CSR build unchanged (R3): hist -> scan -> fill
//   - Wt pre-transpose+cast: [Wl;Wr] (256x128 f32) -> Wt[col][k] bf16, once
//   - csr_mean: wave/node gather (bf16 src for layer1 if ws fits), bf16 mean out
//   - GEMM: A=[mean|x]bf16 via LDS (stride 72 = conflict-free b128), B from Wt,
//     MFMA accumulate fp32, bias(+relu), h kept fp32 in d_out (absmax hedge;
//     same-block read-before-write aliasing proven in R3).

#define N_NODES 100000
#define N_EDGES 1600000
#define F 128
#define NB 391

typedef __attribute__((ext_vector_type(8))) short short8;
typedef __attribute__((ext_vector_type(4))) float f32x4;

__device__ __forceinline__ unsigned short f2bf(float f) {
    union { __hip_bfloat16 h; unsigned short u; } cv;
    cv.h = __float2bfloat16(f);
    return cv.u;
}
__device__ __forceinline__ float bf2f(unsigned short u) {
    return __uint_as_float(((unsigned)u) << 16);
}

// ---------------- CSR build (unchanged from R3) ----------------
__global__ __launch_bounds__(256) void hist_kernel(
    const int* __restrict__ dst, int* __restrict__ deg_i, int E)
{
    int e = blockIdx.x * 256 + threadIdx.x;
    if (e < E) atomicAdd(&deg_i[dst[e]], 1);
}

__global__ __launch_bounds__(256) void partial_sum_kernel(
    const int* __restrict__ deg_i, int* __restrict__ partial, int N)
{
    int i = blockIdx.x * 256 + threadIdx.x;
    int d = (i < N) ? deg_i[i] : 0;
#pragma unroll
    for (int off = 32; off > 0; off >>= 1) d += __shfl_down(d, off, 64);
    __shared__ int ws[4];
    if ((threadIdx.x & 63) == 0) ws[threadIdx.x >> 6] = d;
    __syncthreads();
    if (threadIdx.x == 0) partial[blockIdx.x] = ws[0] + ws[1] + ws[2] + ws[3];
}

__global__ __launch_bounds__(512) void scan_partial_kernel(int* partial)
{
    __shared__ int s[512];
    int t = threadIdx.x;
    s[t] = (t < NB) ? partial[t] : 0;
    __syncthreads();
#pragma unroll
    for (int off = 1; off < 512; off <<= 1) {
        int v = (t >= off) ? s[t - off] : 0;
        __syncthreads();
        s[t] += v;
        __syncthreads();
    }
    partial[t] = (t == 0) ? 0 : s[t - 1];
}

__global__ __launch_bounds__(256) void rowptr_kernel(
    const int* __restrict__ deg_i, const int* __restrict__ partial,
    int* __restrict__ rowptr, int* __restrict__ cursor, int N)
{
    __shared__ int s[256];
    int t = threadIdx.x;
    int i = blockIdx.x * 256 + t;
    int d = (i < N) ? deg_i[i] : 0;
    s[t] = d;
    __syncthreads();
#pragma unroll
    for (int off = 1; off < 256; off <<= 1) {
        int v = (t >= off) ? s[t - off] : 0;
        __syncthreads();
        s[t] += v;
        __syncthreads();
    }
    if (i < N) {
        int r = partial[blockIdx.x] + s[t] - d;
        rowptr[i] = r;
        cursor[i] = r;
    }
}

__global__ __launch_bounds__(256) void fill_kernel(
    const int* __restrict__ src, const int* __restrict__ dst,
    int* __restrict__ cursor, int* __restrict__ csr_src, int E)
{
    int e = blockIdx.x * 256 + threadIdx.x;
    if (e < E) {
        int pos = atomicAdd(&cursor[dst[e]], 1);
        csr_src[pos] = src[e];
    }
}

// ---------------- weight transpose+cast: Wt[layer][col][k] bf16 ----------------
__global__ __launch_bounds__(256) void wt_kernel(
    const float* __restrict__ Wl1, const float* __restrict__ Wr1,
    const float* __restrict__ Wl2, const float* __restrict__ Wr2,
    unsigned short* __restrict__ wt)
{
    int e = blockIdx.x * 256 + threadIdx.x;   // 0..65535
    int layer = e >> 15;
    int idx = e & 32767;
    int k = idx >> 7;      // 0..255
    int c = idx & 127;
    const float* W = (layer == 0) ? (k < 128 ? Wl1 : Wr1)
                                  : (k < 128 ? Wl2 : Wr2);
    float v = W[(k & 127) * 128 + c];
    wt[layer * 32768 + c * 256 + k] = f2bf(v);
}

// ---------------- cast x -> bf16 ----------------
__global__ __launch_bounds__(256) void cast_kernel(
    const float* __restrict__ x, unsigned short* __restrict__ xb, int total4)
{
    int i = blockIdx.x * 256 + threadIdx.x;
    if (i >= total4) return;
    float4 v = ((const float4*)x)[i];
    unsigned lo = ((unsigned)f2bf(v.y) << 16) | f2bf(v.x);
    unsigned hi = ((unsigned)f2bf(v.w) << 16) | f2bf(v.z);
    ((uint2*)xb)[i] = make_uint2(lo, hi);
}

// ---------------- aggregate: mean over in-neighbors, bf16 out ----------------
template <bool SRC_BF16>
__global__ __launch_bounds__(256) void csr_mean_kernel(
    const void* __restrict__ feat, const int* __restrict__ rowptr,
    const int* __restrict__ deg_i, const int* __restrict__ csr_src,
    unsigned int* __restrict__ mean, int N)
{
    int n = blockIdx.x * 4 + (threadIdx.x >> 6);
    int lane = threadIdx.x & 63;
    if (n >= N) return;
    int start = rowptr[n];
    int dg = deg_i[n];
    int end = start + dg;
    float ax = 0.f, ay = 0.f;
    int e = start;
    for (; e + 1 < end; e += 2) {
        int s0 = csr_src[e], s1 = csr_src[e + 1];
        if (SRC_BF16) {
            unsigned u0 = ((const unsigned*)feat)[s0 * 64 + lane];
            unsigned u1 = ((const unsigned*)feat)[s1 * 64 + lane];
            ax += bf2f((unsigned short)u0) + bf2f((unsigned short)u1);
            ay += bf2f((unsigned short)(u0 >> 16)) + bf2f((unsigned short)(u1 >> 16));
        } else {
            float2 v0 = ((const float2*)feat)[s0 * 64 + lane];
            float2 v1 = ((const float2*)feat)[s1 * 64 + lane];
            ax += v0.x + v1.x;
            ay += v0.y + v1.y;
        }
    }
    if (e < end) {
        int s0 = csr_src[e];
        if (SRC_BF16) {
            unsigned u0 = ((const unsigned*)feat)[s0 * 64 + lane];
            ax += bf2f((unsigned short)u0);
            ay += bf2f((unsigned short)(u0 >> 16));
        } else {
            float2 v0 = ((const float2*)feat)[s0 * 64 + lane];
            ax += v0.x;
            ay += v0.y;
        }
    }
    float r = 1.0f / fmaxf((float)dg, 1.0f);
    mean[n * 64 + lane] = ((unsigned)f2bf(ay * r) << 16) | f2bf(ax * r);
}

// ---------------- MFMA GEMM: out = [mean|x] @ Wt^T + bias (+relu) ----------------
// 256 thr = 4 waves; block computes 64 rows x 128 cols; K=256 in 4 chunks of 64.
// Safe for xin==outp: block reads only own rows (chunks 2,3) before epilogue.
template <bool RELU, bool XSRC_BF16>
__global__ __launch_bounds__(256) void sage_gemm_mfma(
    const unsigned short* __restrict__ meanb,
    const void* __restrict__ xin,
    const unsigned short* __restrict__ wt,   // [128 cols][256 k] bf16
    const float* __restrict__ bias,
    float* __restrict__ outp, int N)
{
    __shared__ unsigned short As[64][72];    // stride 144 B: 16B-aligned, conflict-free b128
    __shared__ unsigned short Bs[128][72];

    const int t = threadIdx.x;
    const int block_row = blockIdx.x * 64;
    const int lane = t & 63;
    const int w = t >> 6;
    const int m = lane & 15;
    const int kq = lane >> 4;

    f32x4 acc[8];
#pragma unroll
    for (int i = 0; i < 8; ++i) acc[i] = (f32x4){0.f, 0.f, 0.f, 0.f};

    for (int chunk = 0; chunk < 4; ++chunk) {
        const bool is_mean = (chunk < 2);
        const int kbase = (chunk & 1) * 64;

        // ---- A tile: 64 rows x 64 k (each thread: 16 bf16 = 32 B) ----
        {
            int row_l = t >> 2;
            int seg = t & 3;
            int grow = block_row + row_l;
            unsigned short* dstp = &As[row_l][seg * 16];
            if (grow < N) {
                if (is_mean) {
                    const uint4* p = (const uint4*)(meanb + (size_t)grow * F + kbase + seg * 16);
                    ((uint4*)dstp)[0] = p[0];
                    ((uint4*)dstp)[1] = p[1];
                } else if (XSRC_BF16) {
                    const uint4* p = (const uint4*)((const unsigned short*)xin +
                                                    (size_t)grow * F + kbase + seg * 16);
                    ((uint4*)dstp)[0] = p[0];
                    ((uint4*)dstp)[1] = p[1];
                } else {
                    const float4* p = (const float4*)((const float*)xin +
                                                      (size_t)grow * F + kbase + seg * 16);
#pragma unroll
                    for (int q = 0; q < 4; ++q) {
                        float4 v = p[q];
                        unsigned lo = ((unsigned)f2bf(v.y) << 16) | f2bf(v.x);
                        unsigned hi = ((unsigned)f2bf(v.w) << 16) | f2bf(v.z);
                        ((unsigned*)dstp)[q * 2]     = lo;
                        ((unsigned*)dstp)[q * 2 + 1] = hi;
                    }
                }
            } else {
                uint4 z = make_uint4(0, 0, 0, 0);
                ((uint4*)dstp)[0] = z;
                ((uint4*)dstp)[1] = z;
            }
        }
        // ---- B tile: 128 cols x 64 k from Wt (each thread: 32 bf16 = 64 B) ----
        {
            int c = t >> 1;
            int half = t & 1;
            const uint4* p = (const uint4*)(wt + c * 256 + chunk * 64 + half * 32);
            unsigned short* dstp = &Bs[c][half * 32];
            ((uint4*)dstp)[0] = p[0];
            ((uint4*)dstp)[1] = p[1];
            ((uint4*)dstp)[2] = p[2];
            ((uint4*)dstp)[3] = p[3];
        }
        __syncthreads();

        // ---- MFMA: A[m=lane&15][k=(lane>>4)*8+j], B[k][n=lane&15] ----
#pragma unroll
        for (int ks = 0; ks < 2; ++ks) {
            short8 a = *(const short8*)&As[w * 16 + m][ks * 32 + kq * 8];
#pragma unroll
            for (int tt = 0; tt < 8; ++tt) {
                short8 b = *(const short8*)&Bs[tt * 16 + m][ks * 32 + kq * 8];
                acc[tt] = __builtin_amdgcn_mfma_f32_16x16x32_bf16(a, b, acc[tt], 0, 0, 0);
            }
        }
        __syncthreads();
    }

    // ---- epilogue: C/D row=(lane>>4)*4+reg, col=lane&15 ----
    float bb[8];
#pragma unroll
    for (int tt = 0; tt < 8; ++tt) bb[tt] = bias[tt * 16 + m];
    int rbase = block_row + w * 16 + kq * 4;
#pragma unroll
    for (int r = 0; r < 4; ++r) {
        int grow = rbase + r;
        if (grow < N) {
#pragma unroll
            for (int tt = 0; tt < 8; ++tt) {
                float v = acc[tt][r] + bb[tt];
                if (RELU) v = fmaxf(v, 0.f);
                outp[(size_t)grow * F + tt * 16 + m] = v;
            }
        }
    }
}

extern "C" void kernel_launch(void* const* d_in, const int* in_sizes, int n_in,
                              void* d_out, int out_size, void* d_ws, size_t ws_size,
                              hipStream_t stream) {
    const float* x    = (const float*)d_in[0];
    const int*   ei   = (const int*)d_in[1];    // int32 (harness converts int64)
    const float* W_l1 = (const float*)d_in[2];
    const float* W_r1 = (const float*)d_in[3];
    const float* b1   = (const float*)d_in[4];
    const float* W_l2 = (const float*)d_in[5];
    const float* W_r2 = (const float*)d_in[6];
    const float* b2   = (const float*)d_in[7];
    float* out        = (float*)d_out;

    const int N = N_NODES;
    const int E = N_EDGES;
    const int* srcv = ei;
    const int* dstv = ei + E;

    // ---- workspace layout (bytes) ----
    const size_t rowptr_off = 401408;
    const size_t cursor_off = 802816;
    const size_t part_off   = 1204224;
    const size_t csr_off    = 1206272;                 // int[1.6M] -> ends 7,606,272
    const size_t wt_off     = 7606272;                 // bf16[2][128][256] -> ends 7,737,344
    const size_t mean_off   = 7737344;                 // bf16[N*F] -> ends 33,337,344
    const size_t xb_off     = 33337344;                // bf16[N*F] -> ends 58,937,344
    const size_t need_t0    = 33337344;
    const size_t need_t1    = 58937344;

    if (ws_size < need_t0) return;  // clean validation failure as diagnostic
    const bool use_xb = (ws_size >= need_t1);

    char* ws = (char*)d_ws;
    int* deg_i   = (int*)ws;
    int* rowptr  = (int*)(ws + rowptr_off);
    int* cursor  = (int*)(ws + cursor_off);
    int* partial = (int*)(ws + part_off);
    int* csr_src = (int*)(ws + csr_off);
    unsigned short* wt    = (unsigned short*)(ws + wt_off);
    unsigned int*   meanu = (unsigned int*)(ws + mean_off);
    const unsigned short* meanb = (const unsigned short*)(ws + mean_off);
    unsigned short* xb    = (unsigned short*)(ws + xb_off);

    // ---- CSR build + weight prep ----
    hipMemsetAsync(deg_i, 0, (size_t)N * sizeof(int), stream);
    hist_kernel<<<dim3((E + 255) / 256), dim3(256), 0, stream>>>(dstv, deg_i, E);
    partial_sum_kernel<<<dim3(NB), dim3(256), 0, stream>>>(deg_i, partial, N);
    scan_partial_kernel<<<dim3(1), dim3(512), 0, stream>>>(partial);
    rowptr_kernel<<<dim3(NB), dim3(256), 0, stream>>>(deg_i, partial, rowptr, cursor, N);
    fill_kernel<<<dim3((E + 255) / 256), dim3(256), 0, stream>>>(srcv, dstv, cursor, csr_src, E);
    wt_kernel<<<dim3(256), dim3(256), 0, stream>>>(W_l1, W_r1, W_l2, W_r2, wt);
    if (use_xb)
        cast_kernel<<<dim3((N * F / 4 + 255) / 256), dim3(256), 0, stream>>>(x, xb, N * F / 4);

    dim3 ablock(256), agrid((N + 3) / 4);
    dim3 gblock(256), ggrid((N + 63) / 64);

    // ---- layer 1 (h fp32 -> d_out) ----
    if (use_xb) {
        csr_mean_kernel<true><<<agrid, ablock, 0, stream>>>(xb, rowptr, deg_i, csr_src, meanu, N);
        sage_gemm_mfma<true, true><<<ggrid, gblock, 0, stream>>>(meanb, xb, wt, b1, out, N);
    } else {
        csr_mean_kernel<false><<<agrid, ablock, 0, stream>>>(x, rowptr, deg_i, csr_src, meanu, N);
        sage_gemm_mfma<true, false><<<ggrid, gblock, 0, stream>>>(meanb, x, wt, b1, out, N);
    }

    // ---- layer 2 (reads h fp32 from d_out, writes d_out) ----
    csr_mean_kernel<false><<<agrid, ablock, 0, stream>>>(out, rowptr, deg_i, csr_src, meanu, N);
    sage_gemm_mfma<false, false><<<ggrid, gblock, 0, stream>>>(meanb, out, wt + 32768, b2, out, N);
}